// Round 13
// baseline (378.733 us; speedup 1.0000x reference)
//
#include <hip/hip_runtime.h>
#include <cstdint>

// Shapes: B=8, C=256, H=W=64 -> N=4096, d=32, groups=32 (8 ch/group)

typedef __bf16 bf16x8 __attribute__((ext_vector_type(8)));
typedef float f32x4 __attribute__((ext_vector_type(4)));
typedef float f32x16 __attribute__((ext_vector_type(16)));
typedef unsigned int u32x4 __attribute__((ext_vector_type(4)));
typedef unsigned short u16x4 __attribute__((ext_vector_type(4)));
typedef unsigned short u16x8 __attribute__((ext_vector_type(8)));

#define DEVI __device__ __forceinline__

DEVI unsigned short f2bf(float f) {
    __bf16 h = (__bf16)f;               // RNE fptrunc
    return __builtin_bit_cast(unsigned short, h);
}
DEVI float bf2f(unsigned short u) {
    unsigned int x = ((unsigned int)u) << 16;
    return __builtin_bit_cast(float, x);
}

DEVI f32x4 mfma16(bf16x8 a, bf16x8 b, f32x4 c) {
    return __builtin_amdgcn_mfma_f32_16x16x32_bf16(a, b, c, 0, 0, 0);
}
DEVI f32x16 mfma32(bf16x8 a, bf16x8 b, f32x16 c) {
    return __builtin_amdgcn_mfma_f32_32x32x16_bf16(a, b, c, 0, 0, 0);
}

// async global->LDS, 16B per lane, wave-uniform LDS base + lane*16
DEVI void glds16(const unsigned short* g, unsigned short* l) {
    const __attribute__((address_space(1))) unsigned int* gp =
        reinterpret_cast<const __attribute__((address_space(1))) unsigned int*>(
            reinterpret_cast<uintptr_t>(g));
    __attribute__((address_space(3))) unsigned int* lp =
        reinterpret_cast<__attribute__((address_space(3))) unsigned int*>(
            reinterpret_cast<uintptr_t>(l));
    __builtin_amdgcn_global_load_lds(gp, lp, 16, 0, 0);
}

// raw barrier without the compiler's vmcnt(0)-drain; manual waits only
DEVI void barrier_raw() {
    asm volatile("" ::: "memory");
    __builtin_amdgcn_s_barrier();
    asm volatile("" ::: "memory");
}
DEVI void wait_vm0() {
    // SIMM16: vmcnt[3:0]=0, expcnt[6:4]=7, lgkmcnt[13:8]=0x3F, vmcnt[5:4]=0
    __builtin_amdgcn_s_waitcnt(0x3F70);
}

// log2(e)/sqrt(32): folded into Wq so S exits QK-MFMA in exp2 domain
#define QSCALE 0.2550663133f
#define MFIX   12.0f

// ---------------- group norm -> h^T (B*N, C) bf16 ----------------
// Single-read: reduction and normalize passes use the same cv[8] registers
// (32 VGPRs across the reduction; bitwise-identical per-thread sum order).
__global__ __launch_bounds__(1024) void k_gnorm(
        const float* __restrict__ x, const float* __restrict__ gw,
        const float* __restrict__ gb, unsigned short* __restrict__ ht) {
    int bg = blockIdx.x;               // 256 blocks = 8 batches * 32 groups
    int b = bg >> 5, g = bg & 31;
    const float* xb = x + ((size_t)(b * 256 + g * 8)) * 4096;  // 8 contiguous rows
    int t = threadIdx.x;
    int n0 = t * 4;
    f32x4 cv[8];
    #pragma unroll
    for (int c = 0; c < 8; c++) cv[c] = *(const f32x4*)(xb + c * 4096 + n0);
    float s1 = 0.f, s2 = 0.f;
    #pragma unroll
    for (int c = 0; c < 8; c++) {
        #pragma unroll
        for (int j = 0; j < 4; j++) { s1 += cv[c][j]; s2 += cv[c][j] * cv[c][j]; }
    }
    #pragma unroll
    for (int off = 1; off < 64; off <<= 1) {
        s1 += __shfl_xor(s1, off);
        s2 += __shfl_xor(s2, off);
    }
    __shared__ float red[34];
    int wv_ = t >> 6;
    if ((t & 63) == 0) { red[wv_ * 2] = s1; red[wv_ * 2 + 1] = s2; }
    __syncthreads();
    if (t == 0) {
        float a = 0.f, q = 0.f;
        #pragma unroll
        for (int i = 0; i < 16; i++) { a += red[i * 2]; q += red[i * 2 + 1]; }
        float mean = a * (1.f / 32768.f);
        float var = q * (1.f / 32768.f) - mean * mean;
        red[32] = mean; red[33] = rsqrtf(var + 1e-5f);
    }
    __syncthreads();
    float mean = red[32], rstd = red[33];
    float wv8[8], bv8[8];
    #pragma unroll
    for (int c = 0; c < 8; c++) { wv8[c] = gw[g * 8 + c] * rstd; bv8[c] = gb[g * 8 + c] - mean * rstd * gw[g * 8 + c]; }
    #pragma unroll
    for (int j = 0; j < 4; j++) {
        u16x8 pk;
        #pragma unroll
        for (int c = 0; c < 8; c++) pk[c] = f2bf(cv[c][j] * wv8[c] + bv8[c]);
        *(u16x8*)(&ht[((size_t)(b * 4096 + n0 + j)) * 256 + g * 8]) = pk;  // 16B store
    }
}

// ---------------- GEMM (merged QK+V projection)  C = A[M x 256] * W^T ----------------
// Weights read as fp32, converted to bf16 during B-staging (bit-identical
// f2bf RNE; weights KB-scale, cache-resident).
// y==0: Wq(x QSCALE, rows 0..31)+Wk(rows 32..63) -> qk row-major (ldout=64);
// y>=1: Wv -> Vt[b][o][n] bf16 transposed, key-dim bit2<->bit3 swap (n0=(y-1)*64).
// 2D grid, 256-thread blocks, ~4 blocks/CU: r11 lesson — these small-K GEMMs
// are occupancy-throughput machines; block-level parallelism beats staging
// reduction (the 1-block/CU fused oproj lost ~15 us).
__global__ __launch_bounds__(256) void k_qkvproj(
        const unsigned short* __restrict__ A, void* __restrict__ outp, int ldout,
        const float* __restrict__ wqf, const float* __restrict__ wkf,
        const float* __restrict__ wvf, void* __restrict__ outp2) {
    __shared__ unsigned short lA[128 * 72];
    __shared__ unsigned short lB[64 * 72];
    int t = threadIdx.x;
    int m0 = blockIdx.x * 128;
    int n0 = (blockIdx.y == 0) ? 0 : (blockIdx.y - 1) * 64;
    int w = t >> 6, lane = t & 63, l15 = lane & 15, quad = lane >> 4;
    f32x4 z4 = {0.f, 0.f, 0.f, 0.f};
    f32x4 acc[2][4];
    #pragma unroll
    for (int i = 0; i < 2; i++)
        #pragma unroll
        for (int j = 0; j < 4; j++) acc[i][j] = z4;

    // fp32 weight row fetch + convert: 8 bf16 for (tile row, global col gc)
    auto ldB8 = [&](int row, int gc) -> u16x8 {
        const float* src;
        float sc = 1.f;
        if (blockIdx.y == 0) {
            if (row < 32) { src = wqf + (size_t)row * 256 + gc; sc = QSCALE; }
            else          { src = wkf + (size_t)(row - 32) * 256 + gc; }
        } else {
            src = wvf + (size_t)(n0 + row) * 256 + gc;
        }
        f32x4 a = *(const f32x4*)src;
        f32x4 b2 = *(const f32x4*)(src + 4);
        u16x8 r;
        #pragma unroll
        for (int j = 0; j < 4; j++) { r[j] = f2bf(a[j] * sc); r[4 + j] = f2bf(b2[j] * sc); }
        return r;
    };

    for (int kb = 0; kb < 4; kb++) {
        #pragma unroll
        for (int i = 0; i < 4; i++) {
            int ch = i * 256 + t;
            int row = ch >> 3, col = (ch & 7) * 8;
            u32x4 v = *(const u32x4*)(A + (size_t)(m0 + row) * 256 + kb * 64 + col);
            *(u32x4*)(&lA[row * 72 + col]) = v;
        }
        #pragma unroll
        for (int i = 0; i < 2; i++) {
            int ch = i * 256 + t;
            int row = ch >> 3, col = (ch & 7) * 8;
            u16x8 v = ldB8(row, kb * 64 + col);
            *(u16x8*)(&lB[row * 72 + col]) = v;
        }
        __syncthreads();
        #pragma unroll
        for (int ks = 0; ks < 2; ks++) {
            bf16x8 af[2], bfr[4];
            #pragma unroll
            for (int fr = 0; fr < 2; fr++)
                af[fr] = *(const bf16x8*)(&lA[(w * 32 + fr * 16 + l15) * 72 + ks * 32 + quad * 8]);
            #pragma unroll
            for (int fn = 0; fn < 4; fn++)
                bfr[fn] = *(const bf16x8*)(&lB[(fn * 16 + l15) * 72 + ks * 32 + quad * 8]);
            #pragma unroll
            for (int fr = 0; fr < 2; fr++)
                #pragma unroll
                for (int fn = 0; fn < 4; fn++)
                    acc[fr][fn] = mfma16(af[fr], bfr[fn], acc[fr][fn]);
        }
        __syncthreads();
    }

    if (blockIdx.y == 0) {
        unsigned short* out = (unsigned short*)outp;
        #pragma unroll
        for (int fr = 0; fr < 2; fr++)
            #pragma unroll
            for (int fn = 0; fn < 4; fn++)
                #pragma unroll
                for (int r = 0; r < 4; r++) {
                    int m = m0 + w * 32 + fr * 16 + quad * 4 + r;
                    int n = n0 + fn * 16 + l15;
                    out[(size_t)m * ldout + n] = f2bf(acc[fr][fn][r]);
                }
    } else {
        unsigned short* out = (unsigned short*)outp2;
        int b = m0 >> 12, nb = (m0 & 4095) + w * 32;
        int swq = ((quad & 1) << 1) | (quad >> 1);   // bit2<->bit3 swap of n within 16
        #pragma unroll
        for (int fr = 0; fr < 2; fr++)
            #pragma unroll
            for (int fn = 0; fn < 4; fn++) {
                int o = n0 + fn * 16 + l15;
                int n = nb + fr * 16 + swq * 4;
                u16x4 pk;
                #pragma unroll
                for (int r = 0; r < 4; r++) pk[r] = f2bf(acc[fr][fn][r]);
                *(u16x4*)(&out[(((size_t)(b * 256 + o)) << 12) + n]) = pk;
            }
    }
}

// ---------------- output projection + residual (2D grid, 4 blocks/CU) ----------------
// out[b][o][n] = x + gamma * (Wproj . attn_out). Grid 256 x 4 (64-col slices).
// Measured-best form (r9); the r11 single-block fusion lost ~15 us to occupancy.
__global__ __launch_bounds__(256) void k_oproj(
        const unsigned short* __restrict__ A, float* __restrict__ out,
        const float* __restrict__ xres, const float* __restrict__ gamma,
        const float* __restrict__ wpf) {
    __shared__ unsigned short lA[128 * 72];
    __shared__ unsigned short lB[64 * 72];
    int t = threadIdx.x;
    int m0 = blockIdx.x * 128, n0 = blockIdx.y * 64;
    int w = t >> 6, lane = t & 63, l15 = lane & 15, quad = lane >> 4;
    f32x4 z4 = {0.f, 0.f, 0.f, 0.f};
    f32x4 acc[2][4];
    #pragma unroll
    for (int i = 0; i < 2; i++)
        #pragma unroll
        for (int j = 0; j < 4; j++) acc[i][j] = z4;

    for (int kb = 0; kb < 4; kb++) {
        #pragma unroll
        for (int i = 0; i < 4; i++) {
            int ch = i * 256 + t;
            int row = ch >> 3, col = (ch & 7) * 8;
            u32x4 v = *(const u32x4*)(A + (size_t)(m0 + row) * 256 + kb * 64 + col);
            *(u32x4*)(&lA[row * 72 + col]) = v;
        }
        #pragma unroll
        for (int i = 0; i < 2; i++) {
            int ch = i * 256 + t;
            int row = ch >> 3, col = (ch & 7) * 8;
            const float* src = wpf + (size_t)(n0 + row) * 256 + kb * 64 + col;
            f32x4 a = *(const f32x4*)src;
            f32x4 b2 = *(const f32x4*)(src + 4);
            u16x8 r;
            #pragma unroll
            for (int j = 0; j < 4; j++) { r[j] = f2bf(a[j]); r[4 + j] = f2bf(b2[j]); }
            *(u16x8*)(&lB[row * 72 + col]) = r;
        }
        __syncthreads();
        #pragma unroll
        for (int ks = 0; ks < 2; ks++) {
            bf16x8 af[2], bfr[4];
            #pragma unroll
            for (int fr = 0; fr < 2; fr++)
                af[fr] = *(const bf16x8*)(&lA[(w * 32 + fr * 16 + l15) * 72 + ks * 32 + quad * 8]);
            #pragma unroll
            for (int fn = 0; fn < 4; fn++)
                bfr[fn] = *(const bf16x8*)(&lB[(fn * 16 + l15) * 72 + ks * 32 + quad * 8]);
            #pragma unroll
            for (int fr = 0; fr < 2; fr++)
                #pragma unroll
                for (int fn = 0; fn < 4; fn++)
                    acc[fr][fn] = mfma16(af[fr], bfr[fn], acc[fr][fn]);
        }
        __syncthreads();
    }

    float gm = gamma[0];
    int b = m0 >> 12, nb = (m0 & 4095) + w * 32;
    #pragma unroll
    for (int fr = 0; fr < 2; fr++)
        #pragma unroll
        for (int fn = 0; fn < 4; fn++) {
            int o = n0 + fn * 16 + l15;
            int n = nb + fr * 16 + quad * 4;
            size_t base = (((size_t)(b * 256 + o)) << 12) + n;
            f32x4 xv = *(const f32x4*)(xres + base);
            f32x4 ov;
            #pragma unroll
            for (int r = 0; r < 4; r++) ov[r] = xv[r] + gm * acc[fr][fn][r];
            *(f32x4*)(out + base) = ov;
        }
}

// ---------------- flash attention: 32x32 MFMA, 128-key double bodies, o-split,
//                  512-thread blocks ----------------
// QK: (B*N, 64) bf16 (q cols 0..31 pre-scaled, k cols 32..63).
// Vt: (B, 256, N) bf16, key-dim sigma-permuted (bit2<->bit3 per 16-group).
// Grid 256 = 8 b x 16 qblk(256q) x 2 oh(128 o-chans) -> exactly 1 block/CU.
// 8 waves = 4 qh(64q) x 2 kh. Wave compute = proven round-5 body, UNCHANGED.
//
// r13 change: 128 keys per barrier interval — two sequential 64-key
// sub-computes share one wait_vm0+barrier (32 events instead of 64, and each
// drain has 2x the compute issued under it). Sub-tile b lives at a CONSTANT
// LDS offset (+4KB K, +16KB V) from sub-tile a, so its pointers fold into
// ds_read offset immediates: ~0 new registers (r10's spill came from a new
// pointer set + 3-deep rotation; this has neither).
// sched_barrier(0) between sub-computes pins sub-1 fully before sub-2 ->
// peak liveness identical to the r9 schedule (no St/pa overlap — the r4
// spill mechanism is structurally excluded). Key accumulation order is
// unchanged (keys 0..63 then 64..127 per body) -> bit-identical numerics.
// REGISTER WALL (4 spill incidents r1/r3/r4/r10): arch VGPR budget is
// exactly 128; no cross-barrier register state, no St/pa co-liveness.
// Tripwire: WRITE > 17 MB = spill -> revert to r9 2-buffer 64-key loop.
__global__ __launch_bounds__(512, 2) void k_flash(
        const unsigned short* __restrict__ QK, const unsigned short* __restrict__ Vt,
        unsigned short* __restrict__ Oa) {
    // buffers: K0@0(8KB) V0@8192(32KB) K1@40960(8KB) V1@49152(32KB) = 80KB.
    // Each buffer = two 64-key sub-tiles: Ksub at +4KB, Vsub at +16KB.
    // epilogue reuse: O-partials bytes [0,65536), lsum floats [16384,16896).
    __shared__ __align__(16) char smem[81920];
    int id = blockIdx.x;
    int b = id & 7;                    // batch <-> XCD affinity
    int r3 = id >> 3;
    int oh = r3 & 1, qblk = r3 >> 1;   // o-half, q-block(256)
    int t = threadIdx.x, w = t >> 6, ln = t & 63;
    int l31 = ln & 31, h = ln >> 5;
    int qh = w >> 1, kh = w & 1;       // qh 0..3, kh 0..1
    int q0 = qblk * 256 + qh * 64;     // this wave's 64-q range (2 tiles of 32)

    // persistent Q B-frags: B[k=d][n=q]; lane: q=l31, d = s*16 + h*8 + j
    bf16x8 qb0[2], qb1[2];
    #pragma unroll
    for (int qt2 = 0; qt2 < 2; qt2++) {
        const unsigned short* qrow = QK + ((size_t)(b * 4096 + q0 + qt2 * 32 + l31)) * 64;
        qb0[qt2] = *(const bf16x8*)(qrow + h * 8);
        qb1[qt2] = *(const bf16x8*)(qrow + 16 + h * 8);
    }

    // staging: K tile by waves 0..3 (wave w stages keys w*16..+16), chunk-swizzled
    int cgK = (ln & 3) ^ ((ln >> 2) & 3) ^ ((ln >> 4) & 3);
    const unsigned short* gK = QK + ((size_t)(b * 4096 + (w & 3) * 16 + (ln >> 2))) * 64 + 32 + cgK * 8;
    // V half-tile: wave w stages o-rows oh*128 + w*16..+16 (2 glds16), chunk-swizzled
    int vc8 = (ln & 7) ^ ((ln >> 3) & 7);
    const unsigned short* gV = Vt + (((size_t)(b * 256 + oh * 128 + w * 16 + (ln >> 3))) << 12) + vc8 * 8;

    // double buffers of 128-key tiles: K 8KB + V 32KB each
    unsigned short* lK0 = (unsigned short*)smem;
    unsigned short* lV0 = (unsigned short*)(smem + 8192);
    unsigned short* lK1 = (unsigned short*)(smem + 40960);
    unsigned short* lV1 = (unsigned short*)(smem + 49152);
    unsigned short* sK0 = lK0 + (w & 3) * 512;
    unsigned short* sV0 = lV0 + w * 1024;
    unsigned short* sK1 = lK1 + (w & 3) * 512;
    unsigned short* sV1 = lV1 + w * 1024;

    f32x16 z16;
    #pragma unroll
    for (int i = 0; i < 16; i++) z16[i] = 0.f;
    f32x16 minit;
    #pragma unroll
    for (int i = 0; i < 16; i++) minit[i] = -MFIX;
    f32x16 Oacc[2][4];
    #pragma unroll
    for (int qt2 = 0; qt2 < 2; qt2++)
        #pragma unroll
        for (int i = 0; i < 4; i++) Oacc[qt2][i] = z16;
    float lsum[2] = {0.f, 0.f};        // per-lane partial rowsum (q=l31, this (kh,h) keys)

    // loop-invariant LDS read offsets (sub-b = +2048 shorts K, +8192 shorts V)
    int gl = (l31 & 3) ^ ((l31 >> 2) & 3);
    const unsigned short* kf0p0 = lK0 + (kh * 32 + l31) * 32 + ((0 + h) ^ gl) * 8;
    const unsigned short* kf1p0 = lK0 + (kh * 32 + l31) * 32 + ((2 + h) ^ gl) * 8;
    const unsigned short* kf0p1 = lK1 + (kh * 32 + l31) * 32 + ((0 + h) ^ gl) * 8;
    const unsigned short* kf1p1 = lK1 + (kh * 32 + l31) * 32 + ((2 + h) ^ gl) * 8;
    int slotA = ((kh * 4 + 0 * 2 + h) ^ (ln & 7)) * 8;
    int slotB = ((kh * 4 + 1 * 2 + h) ^ (ln & 7)) * 8;

    auto stage = [&](int kn, unsigned short* sK, unsigned short* sV) {
        if (w < 4) glds16(gK + (size_t)kn * 4096, sK);
        #pragma unroll
        for (int j = 0; j < 2; j++)
            glds16(gV + ((size_t)j * 8 << 12) + kn * 64, sV + j * 512);
    };

    auto compute = [&](const unsigned short* kf0p, const unsigned short* kf1p,
                       const unsigned short* lV) {
        bf16x8 kf0 = *(const bf16x8*)kf0p;
        bf16x8 kf1 = *(const bf16x8*)kf1p;
        bf16x8 pa[2][2];
        #pragma unroll
        for (int qt2 = 0; qt2 < 2; qt2++) {
            f32x16 St = mfma32(kf0, qb0[qt2], minit);
            St = mfma32(kf1, qb1[qt2], St);
            u16x8 p0u, p1u;
            float s = 0.f;
            #pragma unroll
            for (int j = 0; j < 8; j++) {
                float e0 = __builtin_amdgcn_exp2f(St[j]);
                float e1 = __builtin_amdgcn_exp2f(St[8 + j]);
                s += e0 + e1;                       // rowsum in VALU (lane=q, regs=keys)
                p0u[j] = f2bf(e0);
                p1u[j] = f2bf(e1);
            }
            lsum[qt2] += s;
            pa[qt2][0] = __builtin_bit_cast(bf16x8, p0u);
            pa[qt2][1] = __builtin_bit_cast(bf16x8, p1u);
        }
        __builtin_amdgcn_s_setprio(1);
        #pragma unroll
        for (int nt = 0; nt < 4; nt++) {
            bf16x8 vf = *(const bf16x8*)(lV + (nt * 32 + l31) * 64 + slotA);
            Oacc[0][nt] = mfma32(pa[0][0], vf, Oacc[0][nt]);
            Oacc[1][nt] = mfma32(pa[1][0], vf, Oacc[1][nt]);
        }
        #pragma unroll
        for (int nt = 0; nt < 4; nt++) {
            bf16x8 vf = *(const bf16x8*)(lV + (nt * 32 + l31) * 64 + slotB);
            Oacc[0][nt] = mfma32(pa[0][1], vf, Oacc[0][nt]);
            Oacc[1][nt] = mfma32(pa[1][1], vf, Oacc[1][nt]);
        }
        __builtin_amdgcn_s_setprio(0);
    };

    // prolog: stage 128-key tile 0 (two 64-key halves) into buf0
    stage(0, sK0, sV0);
    stage(1, sK0 + 2048, sV0 + 8192);
    // main: 32 bodies of 128 keys; kt counts 64-key tiles, step 4 = 2 bodies
    for (int kt = 0; kt < 64; kt += 4) {
        // --- body A: compute buf0 (subs a,b), prefetch next 128 into buf1 ---
        wait_vm0();                     // drain buf0's loads (issued 1 body ago)
        barrier_raw();
        stage(kt + 2, sK1, sV1);
        stage(kt + 3, sK1 + 2048, sV1 + 8192);
        compute(kf0p0, kf1p0, lV0);
        __builtin_amdgcn_sched_barrier(0);   // pin sub-a before sub-b (liveness = r9)
        compute(kf0p0 + 2048, kf1p0 + 2048, lV0 + 8192);
        // --- body B: compute buf1, prefetch into buf0 ---
        wait_vm0();
        barrier_raw();
        if (kt + 4 < 64) {
            stage(kt + 4, sK0, sV0);
            stage(kt + 5, sK0 + 2048, sV0 + 8192);
        }
        compute(kf0p1, kf1p1, lV1);
        __builtin_amdgcn_sched_barrier(0);
        compute(kf0p1 + 2048, kf1p1 + 2048, lV1 + 8192);
    }
    // finish rowsums: combine the two h-halves (lane l31 and l31+32 hold
    // complementary key subsets for the same q)
    #pragma unroll
    for (int qt2 = 0; qt2 < 2; qt2++) lsum[qt2] += __shfl_xor(lsum[qt2], 32);
    __syncthreads();                    // all LDS reads done before smem reuse

    // ---- epilogue via smem reuse ----
    float* sf = (float*)smem;
    // lsum publish: floats [16384 + kh-region(256) ...], region = 4qh x 2qt2 x 32
    int lbase = (kh ? 16384 : 16640) + qh * 64 + l31;
    sf[lbase] = lsum[0];
    sf[lbase + 32] = lsum[1];
    if (kh == 1) {                      // publish O partials (bf16), 64KB
        #pragma unroll
        for (int qt2 = 0; qt2 < 2; qt2++)
            #pragma unroll
            for (int nt = 0; nt < 4; nt++)
                #pragma unroll
                for (int rg = 0; rg < 2; rg++) {
                    u16x8 pk;
                    #pragma unroll
                    for (int j = 0; j < 8; j++) pk[j] = f2bf(Oacc[qt2][nt][rg * 8 + j]);
                    *(u16x8*)(smem + qh * 16384 + qt2 * 8192 + nt * 2048 + rg * 1024 + ln * 16) = pk;
                }
    }
    __syncthreads();
    if (kh == 0) {                      // reduce + normalize + store
        #pragma unroll
        for (int qt2 = 0; qt2 < 2; qt2++) {
            float rl[16];
            #pragma unroll
            for (int r = 0; r < 16; r++) {
                int row = (r & 3) + 8 * (r >> 2) + 4 * h;
                float l = sf[16384 + qh * 64 + qt2 * 32 + row] +
                          sf[16640 + qh * 64 + qt2 * 32 + row];
                rl[r] = 1.f / l;
            }
            size_t rb = (size_t)(b * 4096 + qblk * 256 + qh * 64 + qt2 * 32);
            #pragma unroll
            for (int nt = 0; nt < 4; nt++)
                #pragma unroll
                for (int rg = 0; rg < 2; rg++) {
                    u16x8 pk = *(const u16x8*)(smem + qh * 16384 + qt2 * 8192 + nt * 2048 + rg * 1024 + ln * 16);
                    #pragma unroll
                    for (int j = 0; j < 8; j++) {
                        int r = rg * 8 + j;
                        float val = (Oacc[qt2][nt][r] + bf2f(pk[j])) * rl[r];
                        int row = (r & 3) + 8 * (r >> 2) + 4 * h;
                        Oa[(rb + row) * 256 + oh * 128 + nt * 32 + l31] = f2bf(val);
                    }
                }
        }
    }
}

// ---------------- launch ----------------
extern "C" void kernel_launch(void* const* d_in, const int* in_sizes, int n_in,
                              void* d_out, int out_size, void* d_ws, size_t ws_size,
                              hipStream_t stream) {
    const float* x  = (const float*)d_in[0];
    const float* nw = (const float*)d_in[1];
    const float* nb = (const float*)d_in[2];
    const float* wq = (const float*)d_in[3];
    const float* wk = (const float*)d_in[4];
    const float* wv = (const float*)d_in[5];
    const float* wp = (const float*)d_in[6];
    const float* gm = (const float*)d_in[7];

    char* p = (char*)d_ws;
    unsigned short* ht  = (unsigned short*)p; p += (size_t)32768 * 256 * 2;  // 16 MB
    unsigned short* qk  = (unsigned short*)p; p += (size_t)32768 * 64 * 2;   // 4 MB
    unsigned short* vt  = (unsigned short*)p; p += (size_t)8 * 256 * 4096 * 2; // 16 MB
    unsigned short* oa  = (unsigned short*)p; p += (size_t)32768 * 256 * 2;  // 16 MB

    k_gnorm<<<dim3(256), dim3(1024), 0, stream>>>(x, nw, nb, ht);
    // merged QK-proj (y=0, Wq/Wk converted in-staging) + V-proj (y=1..4)
    k_qkvproj<<<dim3(256, 5), dim3(256), 0, stream>>>(ht, (void*)qk, 64, wq, wk, wv, (void*)vt);
    k_flash<<<dim3(256), dim3(512), 0, stream>>>(qk, vt, oa);
    // output projection + residual (2D grid, 4 blocks/CU — measured-best form)
    k_oproj<<<dim3(256, 4), dim3(256), 0, stream>>>(oa, (float*)d_out, x, gm, wp);
}

// Round 14
// 221.949 us; speedup vs baseline: 1.7064x; 1.7064x over previous
//
#include <hip/hip_runtime.h>
#include <cstdint>

// Shapes: B=8, C=256, H=W=64 -> N=4096, d=32, groups=32 (8 ch/group)
//
// FINAL CONFIGURATION (r14 = r9/r12 measured-best, 223.5-230.4 us):
//   k_gnorm   : single-read groupnorm -> bf16 h^T
//   k_qkvproj : merged QK+V projection, fp32 weights converted in-staging
//   k_flash   : 512-thread, 2-buffer, wait_vm0 loop — FROZEN (see ledger)
//   k_oproj   : 2D-grid output projection + residual (4 blocks/CU)
// Experiment ledger (13 rounds): flash pipeline-depth x5 -> spill (r1,r3,r4,
// r10,r13; 128 arch-VGPR cap has ZERO headroom at Oacc=128); work-reduction
// (r7) and light-wave TLP (r8) -> per-tile latency floor; 512-thread blocks
// (r9) -> +staging amortization, kept. Non-flash: pack-elim + gnorm single-
// read + qkv-merge kept; XCD swizzle (r1) and oproj fusion (r11) regressed.

typedef __bf16 bf16x8 __attribute__((ext_vector_type(8)));
typedef float f32x4 __attribute__((ext_vector_type(4)));
typedef float f32x16 __attribute__((ext_vector_type(16)));
typedef unsigned int u32x4 __attribute__((ext_vector_type(4)));
typedef unsigned short u16x4 __attribute__((ext_vector_type(4)));
typedef unsigned short u16x8 __attribute__((ext_vector_type(8)));

#define DEVI __device__ __forceinline__

DEVI unsigned short f2bf(float f) {
    __bf16 h = (__bf16)f;               // RNE fptrunc
    return __builtin_bit_cast(unsigned short, h);
}
DEVI float bf2f(unsigned short u) {
    unsigned int x = ((unsigned int)u) << 16;
    return __builtin_bit_cast(float, x);
}

DEVI f32x4 mfma16(bf16x8 a, bf16x8 b, f32x4 c) {
    return __builtin_amdgcn_mfma_f32_16x16x32_bf16(a, b, c, 0, 0, 0);
}
DEVI f32x16 mfma32(bf16x8 a, bf16x8 b, f32x16 c) {
    return __builtin_amdgcn_mfma_f32_32x32x16_bf16(a, b, c, 0, 0, 0);
}

// async global->LDS, 16B per lane, wave-uniform LDS base + lane*16
DEVI void glds16(const unsigned short* g, unsigned short* l) {
    const __attribute__((address_space(1))) unsigned int* gp =
        reinterpret_cast<const __attribute__((address_space(1))) unsigned int*>(
            reinterpret_cast<uintptr_t>(g));
    __attribute__((address_space(3))) unsigned int* lp =
        reinterpret_cast<__attribute__((address_space(3))) unsigned int*>(
            reinterpret_cast<uintptr_t>(l));
    __builtin_amdgcn_global_load_lds(gp, lp, 16, 0, 0);
}

// raw barrier without the compiler's vmcnt(0)-drain; manual waits only
DEVI void barrier_raw() {
    asm volatile("" ::: "memory");
    __builtin_amdgcn_s_barrier();
    asm volatile("" ::: "memory");
}
DEVI void wait_vm0() {
    // SIMM16: vmcnt[3:0]=0, expcnt[6:4]=7, lgkmcnt[13:8]=0x3F, vmcnt[5:4]=0
    __builtin_amdgcn_s_waitcnt(0x3F70);
}

// log2(e)/sqrt(32): folded into Wq so S exits QK-MFMA in exp2 domain
#define QSCALE 0.2550663133f
#define MFIX   12.0f

// ---------------- group norm -> h^T (B*N, C) bf16 ----------------
// Single-read: reduction and normalize passes use the same cv[8] registers
// (32 VGPRs across the reduction; bitwise-identical per-thread sum order).
__global__ __launch_bounds__(1024) void k_gnorm(
        const float* __restrict__ x, const float* __restrict__ gw,
        const float* __restrict__ gb, unsigned short* __restrict__ ht) {
    int bg = blockIdx.x;               // 256 blocks = 8 batches * 32 groups
    int b = bg >> 5, g = bg & 31;
    const float* xb = x + ((size_t)(b * 256 + g * 8)) * 4096;  // 8 contiguous rows
    int t = threadIdx.x;
    int n0 = t * 4;
    f32x4 cv[8];
    #pragma unroll
    for (int c = 0; c < 8; c++) cv[c] = *(const f32x4*)(xb + c * 4096 + n0);
    float s1 = 0.f, s2 = 0.f;
    #pragma unroll
    for (int c = 0; c < 8; c++) {
        #pragma unroll
        for (int j = 0; j < 4; j++) { s1 += cv[c][j]; s2 += cv[c][j] * cv[c][j]; }
    }
    #pragma unroll
    for (int off = 1; off < 64; off <<= 1) {
        s1 += __shfl_xor(s1, off);
        s2 += __shfl_xor(s2, off);
    }
    __shared__ float red[34];
    int wv_ = t >> 6;
    if ((t & 63) == 0) { red[wv_ * 2] = s1; red[wv_ * 2 + 1] = s2; }
    __syncthreads();
    if (t == 0) {
        float a = 0.f, q = 0.f;
        #pragma unroll
        for (int i = 0; i < 16; i++) { a += red[i * 2]; q += red[i * 2 + 1]; }
        float mean = a * (1.f / 32768.f);
        float var = q * (1.f / 32768.f) - mean * mean;
        red[32] = mean; red[33] = rsqrtf(var + 1e-5f);
    }
    __syncthreads();
    float mean = red[32], rstd = red[33];
    float wv8[8], bv8[8];
    #pragma unroll
    for (int c = 0; c < 8; c++) { wv8[c] = gw[g * 8 + c] * rstd; bv8[c] = gb[g * 8 + c] - mean * rstd * gw[g * 8 + c]; }
    #pragma unroll
    for (int j = 0; j < 4; j++) {
        u16x8 pk;
        #pragma unroll
        for (int c = 0; c < 8; c++) pk[c] = f2bf(cv[c][j] * wv8[c] + bv8[c]);
        *(u16x8*)(&ht[((size_t)(b * 4096 + n0 + j)) * 256 + g * 8]) = pk;  // 16B store
    }
}

// ---------------- GEMM (merged QK+V projection)  C = A[M x 256] * W^T ----------------
// Weights read as fp32, converted to bf16 during B-staging (bit-identical
// f2bf RNE; weights KB-scale, cache-resident).
// y==0: Wq(x QSCALE, rows 0..31)+Wk(rows 32..63) -> qk row-major (ldout=64);
// y>=1: Wv -> Vt[b][o][n] bf16 transposed, key-dim bit2<->bit3 swap (n0=(y-1)*64).
// 2D grid, 256-thread blocks, ~4 blocks/CU: r11 lesson — these small-K GEMMs
// are occupancy-throughput machines; block-level parallelism beats staging
// reduction (the 1-block/CU fused oproj lost ~15 us).
__global__ __launch_bounds__(256) void k_qkvproj(
        const unsigned short* __restrict__ A, void* __restrict__ outp, int ldout,
        const float* __restrict__ wqf, const float* __restrict__ wkf,
        const float* __restrict__ wvf, void* __restrict__ outp2) {
    __shared__ unsigned short lA[128 * 72];
    __shared__ unsigned short lB[64 * 72];
    int t = threadIdx.x;
    int m0 = blockIdx.x * 128;
    int n0 = (blockIdx.y == 0) ? 0 : (blockIdx.y - 1) * 64;
    int w = t >> 6, lane = t & 63, l15 = lane & 15, quad = lane >> 4;
    f32x4 z4 = {0.f, 0.f, 0.f, 0.f};
    f32x4 acc[2][4];
    #pragma unroll
    for (int i = 0; i < 2; i++)
        #pragma unroll
        for (int j = 0; j < 4; j++) acc[i][j] = z4;

    // fp32 weight row fetch + convert: 8 bf16 for (tile row, global col gc)
    auto ldB8 = [&](int row, int gc) -> u16x8 {
        const float* src;
        float sc = 1.f;
        if (blockIdx.y == 0) {
            if (row < 32) { src = wqf + (size_t)row * 256 + gc; sc = QSCALE; }
            else          { src = wkf + (size_t)(row - 32) * 256 + gc; }
        } else {
            src = wvf + (size_t)(n0 + row) * 256 + gc;
        }
        f32x4 a = *(const f32x4*)src;
        f32x4 b2 = *(const f32x4*)(src + 4);
        u16x8 r;
        #pragma unroll
        for (int j = 0; j < 4; j++) { r[j] = f2bf(a[j] * sc); r[4 + j] = f2bf(b2[j] * sc); }
        return r;
    };

    for (int kb = 0; kb < 4; kb++) {
        #pragma unroll
        for (int i = 0; i < 4; i++) {
            int ch = i * 256 + t;
            int row = ch >> 3, col = (ch & 7) * 8;
            u32x4 v = *(const u32x4*)(A + (size_t)(m0 + row) * 256 + kb * 64 + col);
            *(u32x4*)(&lA[row * 72 + col]) = v;
        }
        #pragma unroll
        for (int i = 0; i < 2; i++) {
            int ch = i * 256 + t;
            int row = ch >> 3, col = (ch & 7) * 8;
            u16x8 v = ldB8(row, kb * 64 + col);
            *(u16x8*)(&lB[row * 72 + col]) = v;
        }
        __syncthreads();
        #pragma unroll
        for (int ks = 0; ks < 2; ks++) {
            bf16x8 af[2], bfr[4];
            #pragma unroll
            for (int fr = 0; fr < 2; fr++)
                af[fr] = *(const bf16x8*)(&lA[(w * 32 + fr * 16 + l15) * 72 + ks * 32 + quad * 8]);
            #pragma unroll
            for (int fn = 0; fn < 4; fn++)
                bfr[fn] = *(const bf16x8*)(&lB[(fn * 16 + l15) * 72 + ks * 32 + quad * 8]);
            #pragma unroll
            for (int fr = 0; fr < 2; fr++)
                #pragma unroll
                for (int fn = 0; fn < 4; fn++)
                    acc[fr][fn] = mfma16(af[fr], bfr[fn], acc[fr][fn]);
        }
        __syncthreads();
    }

    if (blockIdx.y == 0) {
        unsigned short* out = (unsigned short*)outp;
        #pragma unroll
        for (int fr = 0; fr < 2; fr++)
            #pragma unroll
            for (int fn = 0; fn < 4; fn++)
                #pragma unroll
                for (int r = 0; r < 4; r++) {
                    int m = m0 + w * 32 + fr * 16 + quad * 4 + r;
                    int n = n0 + fn * 16 + l15;
                    out[(size_t)m * ldout + n] = f2bf(acc[fr][fn][r]);
                }
    } else {
        unsigned short* out = (unsigned short*)outp2;
        int b = m0 >> 12, nb = (m0 & 4095) + w * 32;
        int swq = ((quad & 1) << 1) | (quad >> 1);   // bit2<->bit3 swap of n within 16
        #pragma unroll
        for (int fr = 0; fr < 2; fr++)
            #pragma unroll
            for (int fn = 0; fn < 4; fn++) {
                int o = n0 + fn * 16 + l15;
                int n = nb + fr * 16 + swq * 4;
                u16x4 pk;
                #pragma unroll
                for (int r = 0; r < 4; r++) pk[r] = f2bf(acc[fr][fn][r]);
                *(u16x4*)(&out[(((size_t)(b * 256 + o)) << 12) + n]) = pk;
            }
    }
}

// ---------------- output projection + residual (2D grid, 4 blocks/CU) ----------------
// out[b][o][n] = x + gamma * (Wproj . attn_out). Grid 256 x 4 (64-col slices).
// Measured-best form (r9); the r11 single-block fusion lost ~15 us to occupancy.
__global__ __launch_bounds__(256) void k_oproj(
        const unsigned short* __restrict__ A, float* __restrict__ out,
        const float* __restrict__ xres, const float* __restrict__ gamma,
        const float* __restrict__ wpf) {
    __shared__ unsigned short lA[128 * 72];
    __shared__ unsigned short lB[64 * 72];
    int t = threadIdx.x;
    int m0 = blockIdx.x * 128, n0 = blockIdx.y * 64;
    int w = t >> 6, lane = t & 63, l15 = lane & 15, quad = lane >> 4;
    f32x4 z4 = {0.f, 0.f, 0.f, 0.f};
    f32x4 acc[2][4];
    #pragma unroll
    for (int i = 0; i < 2; i++)
        #pragma unroll
        for (int j = 0; j < 4; j++) acc[i][j] = z4;

    for (int kb = 0; kb < 4; kb++) {
        #pragma unroll
        for (int i = 0; i < 4; i++) {
            int ch = i * 256 + t;
            int row = ch >> 3, col = (ch & 7) * 8;
            u32x4 v = *(const u32x4*)(A + (size_t)(m0 + row) * 256 + kb * 64 + col);
            *(u32x4*)(&lA[row * 72 + col]) = v;
        }
        #pragma unroll
        for (int i = 0; i < 2; i++) {
            int ch = i * 256 + t;
            int row = ch >> 3, col = (ch & 7) * 8;
            const float* src = wpf + (size_t)(n0 + row) * 256 + kb * 64 + col;
            f32x4 a = *(const f32x4*)src;
            f32x4 b2 = *(const f32x4*)(src + 4);
            u16x8 r;
            #pragma unroll
            for (int j = 0; j < 4; j++) { r[j] = f2bf(a[j]); r[4 + j] = f2bf(b2[j]); }
            *(u16x8*)(&lB[row * 72 + col]) = r;
        }
        __syncthreads();
        #pragma unroll
        for (int ks = 0; ks < 2; ks++) {
            bf16x8 af[2], bfr[4];
            #pragma unroll
            for (int fr = 0; fr < 2; fr++)
                af[fr] = *(const bf16x8*)(&lA[(w * 32 + fr * 16 + l15) * 72 + ks * 32 + quad * 8]);
            #pragma unroll
            for (int fn = 0; fn < 4; fn++)
                bfr[fn] = *(const bf16x8*)(&lB[(fn * 16 + l15) * 72 + ks * 32 + quad * 8]);
            #pragma unroll
            for (int fr = 0; fr < 2; fr++)
                #pragma unroll
                for (int fn = 0; fn < 4; fn++)
                    acc[fr][fn] = mfma16(af[fr], bfr[fn], acc[fr][fn]);
        }
        __syncthreads();
    }

    float gm = gamma[0];
    int b = m0 >> 12, nb = (m0 & 4095) + w * 32;
    #pragma unroll
    for (int fr = 0; fr < 2; fr++)
        #pragma unroll
        for (int fn = 0; fn < 4; fn++) {
            int o = n0 + fn * 16 + l15;
            int n = nb + fr * 16 + quad * 4;
            size_t base = (((size_t)(b * 256 + o)) << 12) + n;
            f32x4 xv = *(const f32x4*)(xres + base);
            f32x4 ov;
            #pragma unroll
            for (int r = 0; r < 4; r++) ov[r] = xv[r] + gm * acc[fr][fn][r];
            *(f32x4*)(out + base) = ov;
        }
}

// ---------------- flash attention: 32x32 MFMA, dbuf, o-split, 512-thread blocks ----------------
// QK: (B*N, 64) bf16 (q cols 0..31 pre-scaled, k cols 32..63).
// Vt: (B, 256, N) bf16, key-dim sigma-permuted (bit2<->bit3 per 16-group).
// Grid 256 = 8 b x 16 qblk(256q) x 2 oh(128 o-chans) -> exactly 1 block/CU.
// 8 waves = 4 qh(64q) x 2 kh. Wave compute = proven round-5 body.
//
// FROZEN at 92-95.5 us (rounds 9/11/12). FIVE spill incidents from loop-body
// growth: r1 (pa carry), r3 (Q-in-LDS + pa carry), r4 (St0+St1 live), r10
// (3-buffer counted vmcnt), r13 (128-key double body — even constant-offset
// sub-tiles + sched_barrier(0) spilled: the allocator materializes the
// doubled straight-line region's address sets together). The arch budget is
// exactly 128 VGPR with Oacc=128 acc; the r9 body is register-MAXIMAL.
// Do not modify this loop in any way.
__global__ __launch_bounds__(512, 2) void k_flash(
        const unsigned short* __restrict__ QK, const unsigned short* __restrict__ Vt,
        unsigned short* __restrict__ Oa) {
    // buffers: K0@0(4KB) V0@4096(16KB) K1@20480(4KB) V1@24576(16KB) = 40KB
    // epilogue reuse: O-partials bytes [0,65536), lsum floats [16384,16896)
    __shared__ __align__(16) char smem[67584];
    int id = blockIdx.x;
    int b = id & 7;                    // batch <-> XCD affinity
    int r3 = id >> 3;
    int oh = r3 & 1, qblk = r3 >> 1;   // o-half, q-block(256)
    int t = threadIdx.x, w = t >> 6, ln = t & 63;
    int l31 = ln & 31, h = ln >> 5;
    int qh = w >> 1, kh = w & 1;       // qh 0..3, kh 0..1
    int q0 = qblk * 256 + qh * 64;     // this wave's 64-q range (2 tiles of 32)

    // persistent Q B-frags: B[k=d][n=q]; lane: q=l31, d = s*16 + h*8 + j
    bf16x8 qb0[2], qb1[2];
    #pragma unroll
    for (int qt2 = 0; qt2 < 2; qt2++) {
        const unsigned short* qrow = QK + ((size_t)(b * 4096 + q0 + qt2 * 32 + l31)) * 64;
        qb0[qt2] = *(const bf16x8*)(qrow + h * 8);
        qb1[qt2] = *(const bf16x8*)(qrow + 16 + h * 8);
    }

    // staging: K tile by waves 0..3 (wave w stages keys w*16..+16), chunk-swizzled
    int cgK = (ln & 3) ^ ((ln >> 2) & 3) ^ ((ln >> 4) & 3);
    const unsigned short* gK = QK + ((size_t)(b * 4096 + (w & 3) * 16 + (ln >> 2))) * 64 + 32 + cgK * 8;
    // V half-tile: wave w stages o-rows oh*128 + w*16..+16 (2 glds16), chunk-swizzled
    int vc8 = (ln & 7) ^ ((ln >> 3) & 7);
    const unsigned short* gV = Vt + (((size_t)(b * 256 + oh * 128 + w * 16 + (ln >> 3))) << 12) + vc8 * 8;

    // double buffers: K 4KB + V 16KB each
    unsigned short* lK0 = (unsigned short*)smem;
    unsigned short* lV0 = (unsigned short*)(smem + 4096);
    unsigned short* lK1 = (unsigned short*)(smem + 20480);
    unsigned short* lV1 = (unsigned short*)(smem + 24576);
    unsigned short* sK0 = lK0 + (w & 3) * 512;
    unsigned short* sV0 = lV0 + w * 1024;
    unsigned short* sK1 = lK1 + (w & 3) * 512;
    unsigned short* sV1 = lV1 + w * 1024;

    f32x16 z16;
    #pragma unroll
    for (int i = 0; i < 16; i++) z16[i] = 0.f;
    f32x16 minit;
    #pragma unroll
    for (int i = 0; i < 16; i++) minit[i] = -MFIX;
    f32x16 Oacc[2][4];
    #pragma unroll
    for (int qt2 = 0; qt2 < 2; qt2++)
        #pragma unroll
        for (int i = 0; i < 4; i++) Oacc[qt2][i] = z16;
    float lsum[2] = {0.f, 0.f};        // per-lane partial rowsum (q=l31, this (kh,h) keys)

    // loop-invariant LDS read offsets
    int gl = (l31 & 3) ^ ((l31 >> 2) & 3);
    const unsigned short* kf0p0 = lK0 + (kh * 32 + l31) * 32 + ((0 + h) ^ gl) * 8;
    const unsigned short* kf1p0 = lK0 + (kh * 32 + l31) * 32 + ((2 + h) ^ gl) * 8;
    const unsigned short* kf0p1 = lK1 + (kh * 32 + l31) * 32 + ((0 + h) ^ gl) * 8;
    const unsigned short* kf1p1 = lK1 + (kh * 32 + l31) * 32 + ((2 + h) ^ gl) * 8;
    int slotA = ((kh * 4 + 0 * 2 + h) ^ (ln & 7)) * 8;
    int slotB = ((kh * 4 + 1 * 2 + h) ^ (ln & 7)) * 8;

    auto stage = [&](int kn, unsigned short* sK, unsigned short* sV) {
        if (w < 4) glds16(gK + (size_t)kn * 4096, sK);
        #pragma unroll
        for (int j = 0; j < 2; j++)
            glds16(gV + ((size_t)j * 8 << 12) + kn * 64, sV + j * 512);
    };

    auto compute = [&](const unsigned short* kf0p, const unsigned short* kf1p,
                       const unsigned short* lV) {
        bf16x8 kf0 = *(const bf16x8*)kf0p;
        bf16x8 kf1 = *(const bf16x8*)kf1p;
        bf16x8 pa[2][2];
        #pragma unroll
        for (int qt2 = 0; qt2 < 2; qt2++) {
            f32x16 St = mfma32(kf0, qb0[qt2], minit);
            St = mfma32(kf1, qb1[qt2], St);
            u16x8 p0u, p1u;
            float s = 0.f;
            #pragma unroll
            for (int j = 0; j < 8; j++) {
                float e0 = __builtin_amdgcn_exp2f(St[j]);
                float e1 = __builtin_amdgcn_exp2f(St[8 + j]);
                s += e0 + e1;                       // rowsum in VALU (lane=q, regs=keys)
                p0u[j] = f2bf(e0);
                p1u[j] = f2bf(e1);
            }
            lsum[qt2] += s;
            pa[qt2][0] = __builtin_bit_cast(bf16x8, p0u);
            pa[qt2][1] = __builtin_bit_cast(bf16x8, p1u);
        }
        __builtin_amdgcn_s_setprio(1);
        #pragma unroll
        for (int nt = 0; nt < 4; nt++) {
            bf16x8 vf = *(const bf16x8*)(lV + (nt * 32 + l31) * 64 + slotA);
            Oacc[0][nt] = mfma32(pa[0][0], vf, Oacc[0][nt]);
            Oacc[1][nt] = mfma32(pa[1][0], vf, Oacc[1][nt]);
        }
        #pragma unroll
        for (int nt = 0; nt < 4; nt++) {
            bf16x8 vf = *(const bf16x8*)(lV + (nt * 32 + l31) * 64 + slotB);
            Oacc[0][nt] = mfma32(pa[0][1], vf, Oacc[0][nt]);
            Oacc[1][nt] = mfma32(pa[1][1], vf, Oacc[1][nt]);
        }
        __builtin_amdgcn_s_setprio(0);
    };

    stage(0, sK0, sV0);                 // preload tile 0 into buf0
    for (int kt = 0; kt < 64; kt += 2) {
        // --- even tile: compute buf0, prefetch kt+1 into buf1 ---
        wait_vm0();                     // drain buf0's loads (issued 1 iter ago)
        barrier_raw();
        stage(kt + 1, sK1, sV1);
        compute(kf0p0, kf1p0, lV0);
        // --- odd tile: compute buf1, prefetch kt+2 into buf0 ---
        wait_vm0();
        barrier_raw();
        if (kt + 2 < 64) stage(kt + 2, sK0, sV0);
        compute(kf0p1, kf1p1, lV1);
    }
    // finish rowsums: combine the two h-halves (lane l31 and l31+32 hold
    // complementary key subsets for the same q)
    #pragma unroll
    for (int qt2 = 0; qt2 < 2; qt2++) lsum[qt2] += __shfl_xor(lsum[qt2], 32);
    __syncthreads();                    // all LDS reads done before smem reuse

    // ---- epilogue via smem reuse ----
    float* sf = (float*)smem;
    // lsum publish: floats [16384 + kh-region(256) ...], region = 4qh x 2qt2 x 32
    int lbase = (kh ? 16384 : 16640) + qh * 64 + l31;
    sf[lbase] = lsum[0];
    sf[lbase + 32] = lsum[1];
    if (kh == 1) {                      // publish O partials (bf16), 64KB
        #pragma unroll
        for (int qt2 = 0; qt2 < 2; qt2++)
            #pragma unroll
            for (int nt = 0; nt < 4; nt++)
                #pragma unroll
                for (int rg = 0; rg < 2; rg++) {
                    u16x8 pk;
                    #pragma unroll
                    for (int j = 0; j < 8; j++) pk[j] = f2bf(Oacc[qt2][nt][rg * 8 + j]);
                    *(u16x8*)(smem + qh * 16384 + qt2 * 8192 + nt * 2048 + rg * 1024 + ln * 16) = pk;
                }
    }
    __syncthreads();
    if (kh == 0) {                      // reduce + normalize + store
        #pragma unroll
        for (int qt2 = 0; qt2 < 2; qt2++) {
            float rl[16];
            #pragma unroll
            for (int r = 0; r < 16; r++) {
                int row = (r & 3) + 8 * (r >> 2) + 4 * h;
                float l = sf[16384 + qh * 64 + qt2 * 32 + row] +
                          sf[16640 + qh * 64 + qt2 * 32 + row];
                rl[r] = 1.f / l;
            }
            size_t rb = (size_t)(b * 4096 + qblk * 256 + qh * 64 + qt2 * 32);
            #pragma unroll
            for (int nt = 0; nt < 4; nt++)
                #pragma unroll
                for (int rg = 0; rg < 2; rg++) {
                    u16x8 pk = *(const u16x8*)(smem + qh * 16384 + qt2 * 8192 + nt * 2048 + rg * 1024 + ln * 16);
                    #pragma unroll
                    for (int j = 0; j < 8; j++) {
                        int r = rg * 8 + j;
                        float val = (Oacc[qt2][nt][r] + bf2f(pk[j])) * rl[r];
                        int row = (r & 3) + 8 * (r >> 2) + 4 * h;
                        Oa[(rb + row) * 256 + oh * 128 + nt * 32 + l31] = f2bf(val);
                    }
                }
        }
    }
}

// ---------------- launch ----------------
extern "C" void kernel_launch(void* const* d_in, const int* in_sizes, int n_in,
                              void* d_out, int out_size, void* d_ws, size_t ws_size,
                              hipStream_t stream) {
    const float* x  = (const float*)d_in[0];
    const float* nw = (const float*)d_in[1];
    const float* nb = (const float*)d_in[2];
    const float* wq = (const float*)d_in[3];
    const float* wk = (const float*)d_in[4];
    const float* wv = (const float*)d_in[5];
    const float* wp = (const float*)d_in[6];
    const float* gm = (const float*)d_in[7];

    char* p = (char*)d_ws;
    unsigned short* ht  = (unsigned short*)p; p += (size_t)32768 * 256 * 2;  // 16 MB
    unsigned short* qk  = (unsigned short*)p; p += (size_t)32768 * 64 * 2;   // 4 MB
    unsigned short* vt  = (unsigned short*)p; p += (size_t)8 * 256 * 4096 * 2; // 16 MB
    unsigned short* oa  = (unsigned short*)p; p += (size_t)32768 * 256 * 2;  // 16 MB

    k_gnorm<<<dim3(256), dim3(1024), 0, stream>>>(x, nw, nb, ht);
    // merged QK-proj (y=0, Wq/Wk converted in-staging) + V-proj (y=1..4)
    k_qkvproj<<<dim3(256, 5), dim3(256), 0, stream>>>(ht, (void*)qk, 64, wq, wk, wv, (void*)vt);
    k_flash<<<dim3(256), dim3(512), 0, stream>>>(qk, vt, oa);
    // output projection + residual (2D grid, 4 blocks/CU — measured-best form)
    k_oproj<<<dim3(256, 4), dim3(256), 0, stream>>>(oa, (float*)d_out, x, gm, wp);
}